// Round 4
// baseline (262.118 us; speedup 1.0000x reference)
//
#include <hip/hip_runtime.h>
#include <hip/hip_bf16.h>
#include <math.h>

// Problem constants
#define MM 2048   // context length
#define NN 256    // entities
#define LL 128    // query length
#define DD 300    // d2
#define D2 600    // 2*D
#define D4 1200   // 4*D
#define DROOT 17.320508075688775f

// GEMM geometry (gates = X @ Wsel^T), bf16 MFMA
#define KP 608    // K = 600 padded to 608 (19 * 32)
#define NP 960    // N = 900 (i,g,o gates) padded to 960
#define GM 64
#define GN 64
#define GK 32

typedef __attribute__((ext_vector_type(8))) short bf16x8;
typedef __attribute__((ext_vector_type(4))) float f32x4;

__device__ __forceinline__ float sigmoidf_(float x) { return 1.f / (1.f + expf(-x)); }

__device__ __forceinline__ ushort f2bf(float v) {
    union { float f; unsigned u; } x; x.f = v;
    unsigned r = x.u + 0x7fffu + ((x.u >> 16) & 1u);   // round-nearest-even
    return (ushort)(r >> 16);
}

// ---------------------------------------------------------------- K-1: tiled transpose dst[C][R] = src[R][C]^T
#define TT 32
__global__ __launch_bounds__(256) void k_transpose(const float* __restrict__ src,
                                                   float* __restrict__ dst,
                                                   int R, int C) {
    __shared__ float tile[TT][TT + 1];
    int c0 = blockIdx.x * TT, r0 = blockIdx.y * TT;
    int tx = threadIdx.x & 31, ty = threadIdx.x >> 5;   // 32 x 8
    for (int i = ty; i < TT; i += 8) {
        int r = r0 + i, c = c0 + tx;
        tile[i][tx] = (r < R && c < C) ? src[(size_t)r * C + c] : 0.f;
    }
    __syncthreads();
    for (int i = ty; i < TT; i += 8) {
        int r = c0 + i, c = r0 + tx;
        if (r < C && c < R) dst[(size_t)r * R + c] = tile[tx][i];
    }
}

// ---------------------------------------------------------------- K0: W_ih -> bf16, rows reordered [i | g | o], K padded
__global__ __launch_bounds__(256) void k_convW(const float* __restrict__ Wih,
                                               ushort* __restrict__ Wb) {
    int r = blockIdx.x;                       // 0..959
    int src = (r < DD) ? r : r + DD;
    bool valid = (r < 3 * DD);
    for (int e = threadIdx.x; e < KP; e += 256) {
        float v = (valid && e < D2) ? Wih[(size_t)src * D2 + e] : 0.f;
        Wb[(size_t)r * KP + e] = f2bf(v);
    }
}

// ---------------------------------------------------------------- K1: tok2ent (ballot-compaction + coalesced accumulate)
#define T2E_T 512
__global__ __launch_bounds__(T2E_T) void k_tok2ent(const float* __restrict__ ctx,
                                                   const float* __restrict__ binM,
                                                   float* __restrict__ ent) {
    __shared__ int lst[MM];
    __shared__ int wcnt[T2E_T / 64];
    int n = blockIdx.x, t = threadIdx.x;
    int wave = t >> 6, lane = t & 63;
    int total = 0;
    for (int c = 0; c < MM; c += T2E_T) {
        int m = c + t;
        float b = binM[(size_t)m * NN + n];
        unsigned long long mask = __ballot(b != 0.f);
        int prefix = __popcll(mask & ((1ull << lane) - 1ull));
        if (lane == 0) wcnt[wave] = (int)__popcll(mask);
        __syncthreads();
        int wbase = total;
        for (int w = 0; w < wave; ++w) wbase += wcnt[w];
        if (b != 0.f) lst[wbase + prefix] = m;
        int chunk_total = 0;
        for (int w = 0; w < T2E_T / 64; ++w) chunk_total += wcnt[w];
        total += chunk_total;
        __syncthreads();
    }
    if (t < DD) {
        float sum = 0.f, mx = 0.f;    // max includes zeros of non-members
        int i = 0;
        for (; i + 4 <= total; i += 4) {
            float v0 = ctx[(size_t)lst[i] * DD + t];
            float v1 = ctx[(size_t)lst[i + 1] * DD + t];
            float v2 = ctx[(size_t)lst[i + 2] * DD + t];
            float v3 = ctx[(size_t)lst[i + 3] * DD + t];
            sum += v0; mx = fmaxf(mx, v0);
            sum += v1; mx = fmaxf(mx, v1);
            sum += v2; mx = fmaxf(mx, v2);
            sum += v3; mx = fmaxf(mx, v3);
        }
        for (; i < total; ++i) {
            float v = ctx[(size_t)lst[i] * DD + t];
            sum += v; mx = fmaxf(mx, v);
        }
        ent[n * D2 + t]      = sum * (1.f / MM);
        ent[n * D2 + DD + t] = mx;
    }
}

// ---------------------------------------------------------------- K2: qprep = mean-pool query then @V  (1 block)
__global__ __launch_bounds__(640) void k_qprep(const float* __restrict__ query,
                                               const float* __restrict__ V,
                                               float* __restrict__ qV) {
    __shared__ float qp[DD];
    int t = threadIdx.x;
    if (t < DD) {
        float s = 0.f;
        for (int l = 0; l < LL; ++l) s += query[l * DD + t];
        qp[t] = s * (1.f / LL);
    }
    __syncthreads();
    if (t < D2) {
        float s = 0.f;
        for (int d = 0; d < DD; ++d) s += qp[d] * V[d * D2 + t];
        qV[t] = s;
    }
}

// ---------------------------------------------------------------- K3: hidden (+gamma fused) ; a_i ; c_j   [Ut = U^T, coalesced]
__global__ __launch_bounds__(320) void k_hidden(const float* __restrict__ ent,
                                                const float* __restrict__ qV,
                                                const float* __restrict__ Ut,
                                                const float* __restrict__ bvec,
                                                const float* __restrict__ W,
                                                float* __restrict__ hidden,
                                                float* __restrict__ a_i,
                                                float* __restrict__ c_j) {
    __shared__ float e_s[D2];
    __shared__ float red[2][5];
    __shared__ float sig_s;
    int n = blockIdx.x, t = threadIdx.x;
    float part = 0.f;
    for (int k = t; k < D2; k += 320) {
        float e = ent[n * D2 + k];
        e_s[k] = e;
        part += e * qV[k];
    }
    for (int off = 32; off; off >>= 1) part += __shfl_down(part, off);
    if ((t & 63) == 0) red[0][t >> 6] = part;
    __syncthreads();
    if (t == 0) sig_s = sigmoidf_((red[0][0] + red[0][1] + red[0][2] + red[0][3] + red[0][4]) / DROOT);
    __syncthreads();
    float sg = sig_s;
    float h = 0.f, wa = 0.f, wc = 0.f;
    if (t < DD) {
        float acc = 0.f;
        const float* up = Ut + t;
        #pragma unroll 4
        for (int k = 0; k < D2; ++k) acc += e_s[k] * up[(size_t)k * DD];
        h = sg * acc + bvec[t];
        hidden[n * DD + t] = h;
        wa = h * W[t];
        wc = h * W[DD + t];
    }
    for (int off = 32; off; off >>= 1) { wa += __shfl_down(wa, off); wc += __shfl_down(wc, off); }
    __syncthreads();
    if ((t & 63) == 0) { red[0][t >> 6] = wa; red[1][t >> 6] = wc; }
    __syncthreads();
    if (t == 0) {
        float A = 0.f, C = 0.f;
        for (int w = 0; w < 5; ++w) { A += red[0][w]; C += red[1][w]; }
        a_i[n] = A; c_j[n] = C;
    }
}

// ---------------------------------------------------------------- K4: alphas = softmax(betas, axis=1)
__global__ __launch_bounds__(256) void k_alphas(const float* __restrict__ adj,
                                                const float* __restrict__ ai,
                                                const float* __restrict__ cj,
                                                float* __restrict__ alphas) {
    __shared__ float red[4];
    __shared__ float bc[2];
    int i = blockIdx.x, j = threadIdx.x;
    float beta = 0.f;
    if (adj[i * NN + j] > 0.f) {
        float v = ai[i] + cj[j];
        beta = (v > 0.f) ? v : 0.01f * v;
    }
    float wm = beta;
    for (int off = 32; off; off >>= 1) wm = fmaxf(wm, __shfl_down(wm, off));
    if ((j & 63) == 0) red[j >> 6] = wm;
    __syncthreads();
    if (j == 0) bc[0] = fmaxf(fmaxf(red[0], red[1]), fmaxf(red[2], red[3]));
    __syncthreads();
    float e = expf(beta - bc[0]);
    float ws_ = e;
    for (int off = 32; off; off >>= 1) ws_ += __shfl_down(ws_, off);
    __syncthreads();
    if ((j & 63) == 0) red[j >> 6] = ws_;
    __syncthreads();
    if (j == 0) bc[1] = 1.f / (red[0] + red[1] + red[2] + red[3]);
    __syncthreads();
    alphas[i * NN + j] = e * bc[1];
}

// ---------------------------------------------------------------- K5: E_t (+EtT +ce fused)
__global__ __launch_bounds__(320) void k_Et(const float* __restrict__ adj,
                                            const float* __restrict__ alphas,
                                            const float* __restrict__ hidden,
                                            const float* __restrict__ w_att,
                                            const float* __restrict__ b_att,
                                            float* __restrict__ Et,
                                            float* __restrict__ EtT,
                                            float* __restrict__ ce) {
    __shared__ float w_s[NN];
    __shared__ float red5[5];
    int i = blockIdx.x, t = threadIdx.x;
    if (t < NN) w_s[t] = adj[i * NN + t] * alphas[t * NN + i];
    __syncthreads();
    float etv = 0.f;
    if (t < DD) {
        float s = 0.f;
        #pragma unroll 4
        for (int j = 0; j < NN; ++j) s += w_s[j] * hidden[j * DD + t];
        etv = fmaxf(s, 0.f);
        Et[i * DD + t] = etv;
        EtT[(size_t)t * NN + i] = etv;
    }
    float pv = (t < DD) ? etv * w_att[DD + t] : 0.f;
    for (int off = 32; off; off >>= 1) pv += __shfl_down(pv, off);
    if ((t & 63) == 0) red5[t >> 6] = pv;
    __syncthreads();
    if (t == 0) ce[i] = red5[0] + red5[1] + red5[2] + red5[3] + red5[4] + b_att[1];
}

// ---------------------------------------------------------------- K6: S[l,n] (+cq fused) + rowmax   [EtT coalesced]
__global__ __launch_bounds__(256) void k_S(const float* __restrict__ query,
                                           const float* __restrict__ EtT,
                                           const float* __restrict__ w_att,
                                           const float* __restrict__ b_att,
                                           const float* __restrict__ ce,
                                           float* __restrict__ S,
                                           float* __restrict__ rowmax) {
    __shared__ float qw[DD];
    __shared__ float red4[4];
    __shared__ float cql_s;
    int l = blockIdx.x, n = threadIdx.x;
    float part = 0.f;
    for (int d = n; d < DD; d += 256) {
        float qv = query[l * DD + d];
        qw[d] = qv * w_att[2 * DD + d];
        part += qv * w_att[d];
    }
    for (int off = 32; off; off >>= 1) part += __shfl_down(part, off);
    if ((n & 63) == 0) red4[n >> 6] = part;
    __syncthreads();
    if (n == 0) cql_s = red4[0] + red4[1] + red4[2] + red4[3] + b_att[0];
    __syncthreads();
    float s = 0.f;
    #pragma unroll 4
    for (int d = 0; d < DD; ++d) s += qw[d] * EtT[(size_t)d * NN + n];
    float val = cql_s + ce[n] + s + b_att[2];
    S[l * NN + n] = val;
    float wm = val;
    for (int off = 32; off; off >>= 1) wm = fmaxf(wm, __shfl_down(wm, off));
    __syncthreads();
    if ((n & 63) == 0) red4[n >> 6] = wm;
    __syncthreads();
    if (n == 0) rowmax[l] = fmaxf(fmaxf(red4[0], red4[1]), fmaxf(red4[2], red4[3]));
}

// ---------------------------------------------------------------- K7: q2c = softmax(rowmax) @ query  (1 block)
__global__ __launch_bounds__(320) void k_q2c(const float* __restrict__ rowmax,
                                             const float* __restrict__ query,
                                             float* __restrict__ q2c) {
    __shared__ float p[LL];
    __shared__ float red[5];
    __shared__ float bc[2];
    int t = threadIdx.x;
    float v = (t < LL) ? rowmax[t] : -1e30f;
    float wm = v;
    for (int off = 32; off; off >>= 1) wm = fmaxf(wm, __shfl_down(wm, off));
    if ((t & 63) == 0) red[t >> 6] = wm;
    __syncthreads();
    if (t == 0) {
        float m = red[0];
        for (int w = 1; w < 5; ++w) m = fmaxf(m, red[w]);
        bc[0] = m;
    }
    __syncthreads();
    float e = (t < LL) ? expf(v - bc[0]) : 0.f;
    float ws_ = e;
    for (int off = 32; off; off >>= 1) ws_ += __shfl_down(ws_, off);
    __syncthreads();
    if ((t & 63) == 0) red[t >> 6] = ws_;
    __syncthreads();
    if (t == 0) {
        float s = 0.f;
        for (int w = 0; w < 5; ++w) s += red[w];
        bc[1] = 1.f / s;
    }
    __syncthreads();
    if (t < LL) p[t] = e * bc[1];
    __syncthreads();
    if (t < DD) {
        float s = 0.f;
        for (int l = 0; l < LL; ++l) s += p[l] * query[l * DD + t];
        q2c[t] = s;
    }
}

// ---------------------------------------------------------------- K8: bidaf out  [WredT coalesced]
__global__ __launch_bounds__(320) void k_bidaf(const float* __restrict__ S,
                                               const float* __restrict__ rowmax,
                                               const float* __restrict__ Et,
                                               const float* __restrict__ query,
                                               const float* __restrict__ q2c,
                                               const float* __restrict__ WredT,
                                               const float* __restrict__ bred,
                                               float* __restrict__ outq) {
    __shared__ float p[NN];
    __shared__ float red5[5];
    __shared__ float xs[D4];
    __shared__ float invs;
    int l = blockIdx.x, t = threadIdx.x;
    float e = (t < NN) ? expf(S[l * NN + t] - rowmax[l]) : 0.f;
    float v = e;
    for (int off = 32; off; off >>= 1) v += __shfl_down(v, off);
    if ((t & 63) == 0) red5[t >> 6] = v;
    __syncthreads();
    if (t == 0) invs = 1.f / (red5[0] + red5[1] + red5[2] + red5[3] + red5[4]);
    __syncthreads();
    if (t < NN) p[t] = e * invs;
    __syncthreads();
    if (t < DD) {
        float s = 0.f;
        #pragma unroll 4
        for (int j = 0; j < NN; ++j) s += p[j] * Et[(size_t)j * DD + t];
        float qv = query[l * DD + t];
        xs[t] = qv; xs[DD + t] = s; xs[2 * DD + t] = qv * s; xs[3 * DD + t] = qv * q2c[t];
    }
    __syncthreads();
    if (t < DD) {
        float s = bred[t];
        const float* wp = WredT + t;
        #pragma unroll 4
        for (int k = 0; k < D4; ++k) s += xs[k] * wp[(size_t)k * DD];
        outq[l * DD + t] = s;
    }
}

// ---------------------------------------------------------------- K9: Xb(bf16) = [context | bin_M @ E_t | 0-pad]
__global__ __launch_bounds__(320) void k_xbuf(const float* __restrict__ ctx,
                                              const float* __restrict__ binM,
                                              const float* __restrict__ Et,
                                              ushort* __restrict__ Xb) {
    __shared__ int lst[NN];
    __shared__ int wcnt[5];
    __shared__ int total_s;
    int m = blockIdx.x, t = threadIdx.x;
    int wave = t >> 6, lane = t & 63;
    float b = (t < NN) ? binM[(size_t)m * NN + t] : 0.f;
    unsigned long long mask = __ballot(b != 0.f);
    int prefix = __popcll(mask & ((1ull << lane) - 1ull));
    if (lane == 0) wcnt[wave] = (int)__popcll(mask);
    __syncthreads();
    int wbase = 0;
    for (int w = 0; w < wave; ++w) wbase += wcnt[w];
    if (b != 0.f) lst[wbase + prefix] = t;
    if (t == 0) total_s = wcnt[0] + wcnt[1] + wcnt[2] + wcnt[3] + wcnt[4];
    __syncthreads();
    int total = total_s;
    if (t < 8) Xb[(size_t)m * KP + D2 + t] = 0;   // K padding
    if (t >= DD) return;
    Xb[(size_t)m * KP + t] = f2bf(ctx[(size_t)m * DD + t]);
    float s = 0.f;
    for (int i = 0; i < total; ++i) s += Et[(size_t)lst[i] * DD + t];
    Xb[(size_t)m * KP + DD + t] = f2bf(s);
}

// ---------------------------------------------------------------- K10: gates = Xb @ Wb^T  (bf16 MFMA, 64x64 tile)
__global__ __launch_bounds__(256) void k_gemm_gates(const ushort* __restrict__ Xb,
                                                    const ushort* __restrict__ Wb,
                                                    float* __restrict__ gates) {
    __shared__ ushort As[GM * GK];
    __shared__ ushort Bs[GN * GK];
    int m0 = blockIdx.x * GM, n0 = blockIdx.y * GN;
    int tid = threadIdx.x;
    int lane = tid & 63, w = tid >> 6;
    int wm = w >> 1, wn = w & 1;
    int l15 = lane & 15, l4 = lane >> 4;
    f32x4 acc[2][2] = {};
    int srow = tid >> 2, kslot = tid & 3;
    int sidx = srow * GK + ((kslot ^ ((srow >> 1) & 3)) << 3);
    for (int k0 = 0; k0 < KP; k0 += GK) {
        uint4 va = *(const uint4*)(Xb + (size_t)(m0 + srow) * KP + k0 + kslot * 8);
        uint4 vb = *(const uint4*)(Wb + (size_t)(n0 + srow) * KP + k0 + kslot * 8);
        *(uint4*)(As + sidx) = va;
        *(uint4*)(Bs + sidx) = vb;
        __syncthreads();
        bf16x8 af[2], bfr[2];
        #pragma unroll
        for (int mi = 0; mi < 2; ++mi) {
            int row = wm * 32 + mi * 16 + l15;
            af[mi] = *(const bf16x8*)(As + row * GK + ((l4 ^ ((row >> 1) & 3)) << 3));
        }
        #pragma unroll
        for (int ni = 0; ni < 2; ++ni) {
            int row = wn * 32 + ni * 16 + l15;
            bfr[ni] = *(const bf16x8*)(Bs + row * GK + ((l4 ^ ((row >> 1) & 3)) << 3));
        }
        #pragma unroll
        for (int mi = 0; mi < 2; ++mi)
            #pragma unroll
            for (int ni = 0; ni < 2; ++ni)
                acc[mi][ni] = __builtin_amdgcn_mfma_f32_16x16x32_bf16(af[mi], bfr[ni], acc[mi][ni], 0, 0, 0);
        __syncthreads();
    }
    #pragma unroll
    for (int mi = 0; mi < 2; ++mi) {
        #pragma unroll
        for (int ni = 0; ni < 2; ++ni) {
            int gcol = n0 + wn * 32 + ni * 16 + l15;
            int grow = m0 + wm * 32 + mi * 16 + l4 * 4;
            #pragma unroll
            for (int r = 0; r < 4; ++r)
                gates[(size_t)(grow + r) * NP + gcol] = acc[mi][ni][r];
        }
    }
}

// ---------------------------------------------------------------- K11: LSTM-cell epilogue (gates layout: i|g|o, stride NP)
__global__ __launch_bounds__(320) void k_lstm(const float* __restrict__ gates,
                                              const float* __restrict__ bih,
                                              const float* __restrict__ bhh,
                                              float* __restrict__ outc) {
    int m = blockIdx.x, d = threadIdx.x;
    if (d >= DD) return;
    const float* g = gates + (size_t)m * NP;
    float gi = g[d]          + bih[d]          + bhh[d];
    float gg = g[DD + d]     + bih[2 * DD + d] + bhh[2 * DD + d];
    float go = g[2 * DD + d] + bih[3 * DD + d] + bhh[3 * DD + d];
    float c = sigmoidf_(gi) * tanhf(gg);
    outc[m * DD + d] = sigmoidf_(go) * tanhf(c);
}

// ================================================================ launch
extern "C" void kernel_launch(void* const* d_in, const int* in_sizes, int n_in,
                              void* d_out, int out_size, void* d_ws, size_t ws_size,
                              hipStream_t stream) {
    const float* context = (const float*)d_in[0];
    const float* query   = (const float*)d_in[1];
    const float* binM    = (const float*)d_in[2];
    const float* adj     = (const float*)d_in[3];
    const float* V       = (const float*)d_in[4];
    const float* U       = (const float*)d_in[5];
    const float* bvec    = (const float*)d_in[6];
    const float* W       = (const float*)d_in[7];
    const float* w_att   = (const float*)d_in[8];
    const float* b_att   = (const float*)d_in[9];
    const float* W_red   = (const float*)d_in[10];
    const float* b_red   = (const float*)d_in[11];
    const float* W_ih    = (const float*)d_in[12];
    const float* b_ih    = (const float*)d_in[13];
    const float* b_hh    = (const float*)d_in[14];

    float* ws = (float*)d_ws;
    float* ent    = ws;                 // 153600
    float* qV     = ent    + 153600;    // 608
    float* hidden = qV     + 608;       // 76800
    float* a_i    = hidden + 76800;     // 256
    float* c_j    = a_i    + 256;       // 256
    float* alphas = c_j    + 256;       // 65536
    float* Et     = alphas + 65536;     // 76800
    float* EtT    = Et     + 76800;     // 76800
    float* ce     = EtT    + 76800;     // 256
    float* Smat   = ce     + 256;       // 32768
    float* rmax   = Smat   + 32768;     // 128
    float* q2c    = rmax   + 128;       // 304
    float* Ut     = q2c    + 304;       // 180000 (600 x 300)
    float* WredT  = Ut     + 180000;    // 360000 (1200 x 300)
    float* gates  = WredT  + 360000;    // MM*NP = 1966080
    ushort* Xb    = (ushort*)(gates + (size_t)MM * NP);   // MM*KP ushorts
    ushort* Wb    = Xb + (size_t)MM * KP;                 // NP*KP ushorts

    float* outc = (float*)d_out;            // ctx: (M, D)
    float* outq = (float*)d_out + MM * DD;  // qry: (L, D)

    hipLaunchKernelGGL(k_transpose, dim3((D2 + 31) / 32, (DD + 31) / 32), dim3(256), 0, stream, U, Ut, DD, D2);
    hipLaunchKernelGGL(k_transpose, dim3((D4 + 31) / 32, (DD + 31) / 32), dim3(256), 0, stream, W_red, WredT, DD, D4);
    hipLaunchKernelGGL(k_convW,   dim3(NP), dim3(256), 0, stream, W_ih, Wb);
    hipLaunchKernelGGL(k_tok2ent, dim3(NN), dim3(T2E_T), 0, stream, context, binM, ent);
    hipLaunchKernelGGL(k_qprep,   dim3(1),  dim3(640), 0, stream, query, V, qV);
    hipLaunchKernelGGL(k_hidden,  dim3(NN), dim3(320), 0, stream, ent, qV, Ut, bvec, W, hidden, a_i, c_j);
    hipLaunchKernelGGL(k_alphas,  dim3(NN), dim3(256), 0, stream, adj, a_i, c_j, alphas);
    hipLaunchKernelGGL(k_Et,      dim3(NN), dim3(320), 0, stream, adj, alphas, hidden, w_att, b_att, Et, EtT, ce);
    hipLaunchKernelGGL(k_S,       dim3(LL), dim3(256), 0, stream, query, EtT, w_att, b_att, ce, Smat, rmax);
    hipLaunchKernelGGL(k_q2c,     dim3(1),  dim3(320), 0, stream, rmax, query, q2c);
    hipLaunchKernelGGL(k_bidaf,   dim3(LL), dim3(320), 0, stream, Smat, rmax, Et, query, q2c, WredT, b_red, outq);
    hipLaunchKernelGGL(k_xbuf,    dim3(MM), dim3(320), 0, stream, context, binM, Et, Xb);
    hipLaunchKernelGGL(k_gemm_gates, dim3(MM / GM, NP / GN), dim3(256), 0, stream, Xb, Wb, gates);
    hipLaunchKernelGGL(k_lstm,    dim3(MM), dim3(320), 0, stream, gates, b_ih, b_hh, outc);
}

// Round 5
// 157.281 us; speedup vs baseline: 1.6666x; 1.6666x over previous
//
#include <hip/hip_runtime.h>
#include <hip/hip_bf16.h>
#include <math.h>

// Problem constants
#define MM 2048   // context length
#define NN 256    // entities
#define LL 128    // query length
#define DD 300    // d2
#define D2 600    // 2*D
#define D4 1200   // 4*D
#define DROOT 17.320508075688775f

// GEMM geometry (gates = X @ Wsel^T), bf16 MFMA
#define KP 608    // K = 600 padded to 608 (19 * 32)
#define NP 960    // N = 900 (i,g,o gates) padded to 960
#define GM 64
#define GN 64
#define GK 32

typedef __attribute__((ext_vector_type(8))) short bf16x8;
typedef __attribute__((ext_vector_type(4))) float f32x4;

__device__ __forceinline__ float sigmoidf_(float x) { return 1.f / (1.f + expf(-x)); }

__device__ __forceinline__ ushort f2bf(float v) {
    union { float f; unsigned u; } x; x.f = v;
    unsigned r = x.u + 0x7fffu + ((x.u >> 16) & 1u);   // round-nearest-even
    return (ushort)(r >> 16);
}

// ---------------------------------------------------------------- K0: W_ih -> bf16, rows reordered [i | g | o], K padded
__global__ __launch_bounds__(256) void k_convW(const float* __restrict__ Wih,
                                               ushort* __restrict__ Wb) {
    int r = blockIdx.x;                       // 0..959
    int src = (r < DD) ? r : r + DD;
    bool valid = (r < 3 * DD);
    for (int e = threadIdx.x; e < KP; e += 256) {
        float v = (valid && e < D2) ? Wih[(size_t)src * D2 + e] : 0.f;
        Wb[(size_t)r * KP + e] = f2bf(v);
    }
}

// ---------------------------------------------------------------- K1: tok2ent (ballot-compaction + coalesced accumulate)
#define T2E_T 512
__global__ __launch_bounds__(T2E_T) void k_tok2ent(const float* __restrict__ ctx,
                                                   const float* __restrict__ binM,
                                                   float* __restrict__ ent) {
    __shared__ int lst[MM];
    __shared__ int wcnt[T2E_T / 64];
    int n = blockIdx.x, t = threadIdx.x;
    int wave = t >> 6, lane = t & 63;
    int total = 0;
    for (int c = 0; c < MM; c += T2E_T) {
        int m = c + t;
        float b = binM[(size_t)m * NN + n];
        unsigned long long mask = __ballot(b != 0.f);
        int prefix = __popcll(mask & ((1ull << lane) - 1ull));
        if (lane == 0) wcnt[wave] = (int)__popcll(mask);
        __syncthreads();
        int wbase = total;
        for (int w = 0; w < wave; ++w) wbase += wcnt[w];
        if (b != 0.f) lst[wbase + prefix] = m;
        int chunk_total = 0;
        for (int w = 0; w < T2E_T / 64; ++w) chunk_total += wcnt[w];
        total += chunk_total;
        __syncthreads();
    }
    if (t < DD) {
        float sum = 0.f, mx = 0.f;    // max includes zeros of non-members
        int i = 0;
        for (; i + 4 <= total; i += 4) {
            float v0 = ctx[(size_t)lst[i] * DD + t];
            float v1 = ctx[(size_t)lst[i + 1] * DD + t];
            float v2 = ctx[(size_t)lst[i + 2] * DD + t];
            float v3 = ctx[(size_t)lst[i + 3] * DD + t];
            sum += v0; mx = fmaxf(mx, v0);
            sum += v1; mx = fmaxf(mx, v1);
            sum += v2; mx = fmaxf(mx, v2);
            sum += v3; mx = fmaxf(mx, v3);
        }
        for (; i < total; ++i) {
            float v = ctx[(size_t)lst[i] * DD + t];
            sum += v; mx = fmaxf(mx, v);
        }
        ent[n * D2 + t]      = sum * (1.f / MM);
        ent[n * D2 + DD + t] = mx;
    }
}

// ---------------------------------------------------------------- K2: qprep = mean-pool query then @V  (1 block)
__global__ __launch_bounds__(640) void k_qprep(const float* __restrict__ query,
                                               const float* __restrict__ V,
                                               float* __restrict__ qV) {
    __shared__ float qp[DD];
    int t = threadIdx.x;
    if (t < DD) {
        float s = 0.f;
        for (int l = 0; l < LL; ++l) s += query[l * DD + t];
        qp[t] = s * (1.f / LL);
    }
    __syncthreads();
    if (t < D2) {
        float s = 0.f;
        for (int d = 0; d < DD; ++d) s += qp[d] * V[d * D2 + t];
        qV[t] = s;
    }
}

// ---------------------------------------------------------------- K3: hidden (+gamma fused) ; a_i ; c_j
// 960 thr: (d, kslice of 200), float4 loads of original U rows, LDS partial reduce.
__global__ __launch_bounds__(960) void k_hidden(const float* __restrict__ ent,
                                                const float* __restrict__ qV,
                                                const float* __restrict__ U,
                                                const float* __restrict__ bvec,
                                                const float* __restrict__ W,
                                                float* __restrict__ hidden,
                                                float* __restrict__ a_i,
                                                float* __restrict__ c_j) {
    __shared__ alignas(16) float e_s[D2];
    __shared__ float hpart[3][DD];
    __shared__ float red[2][16];
    __shared__ float sig_s;
    int n = blockIdx.x, t = threadIdx.x, wv = t >> 6;
    float part = 0.f;
    if (t < D2) { float e = ent[n * D2 + t]; e_s[t] = e; part = e * qV[t]; }
    for (int off = 32; off; off >>= 1) part += __shfl_down(part, off);
    if ((t & 63) == 0) red[0][wv] = part;
    __syncthreads();
    if (t == 0) {
        float s = 0.f;
        for (int w = 0; w < 15; ++w) s += red[0][w];
        sig_s = sigmoidf_(s / DROOT);
    }
    __syncthreads();
    int d = t % 320, sl = t / 320;
    if (d < DD) {
        const float4* u4 = (const float4*)(U + (size_t)d * D2 + sl * 200);
        const float4* e4 = (const float4*)(e_s + sl * 200);
        float acc = 0.f;
        #pragma unroll 5
        for (int k = 0; k < 50; ++k) {
            float4 a = u4[k], b = e4[k];
            acc += a.x * b.x; acc += a.y * b.y; acc += a.z * b.z; acc += a.w * b.w;
        }
        hpart[sl][d] = acc;
    }
    __syncthreads();
    float wa = 0.f, wc = 0.f;
    if (t < DD) {
        float h = sig_s * (hpart[0][t] + hpart[1][t] + hpart[2][t]) + bvec[t];
        hidden[n * DD + t] = h;
        wa = h * W[t]; wc = h * W[DD + t];
    }
    for (int off = 32; off; off >>= 1) { wa += __shfl_down(wa, off); wc += __shfl_down(wc, off); }
    __syncthreads();
    if ((t & 63) == 0) { red[0][wv] = wa; red[1][wv] = wc; }
    __syncthreads();
    if (t == 0) {
        float A = 0.f, C = 0.f;
        for (int w = 0; w < 15; ++w) { A += red[0][w]; C += red[1][w]; }
        a_i[n] = A; c_j[n] = C;
    }
}

// ---------------------------------------------------------------- K4: alphas = softmax(betas, axis=1)
__global__ __launch_bounds__(256) void k_alphas(const float* __restrict__ adj,
                                                const float* __restrict__ ai,
                                                const float* __restrict__ cj,
                                                float* __restrict__ alphas) {
    __shared__ float red[4];
    __shared__ float bc[2];
    int i = blockIdx.x, j = threadIdx.x;
    float beta = 0.f;
    if (adj[i * NN + j] > 0.f) {
        float v = ai[i] + cj[j];
        beta = (v > 0.f) ? v : 0.01f * v;
    }
    float wm = beta;
    for (int off = 32; off; off >>= 1) wm = fmaxf(wm, __shfl_down(wm, off));
    if ((j & 63) == 0) red[j >> 6] = wm;
    __syncthreads();
    if (j == 0) bc[0] = fmaxf(fmaxf(red[0], red[1]), fmaxf(red[2], red[3]));
    __syncthreads();
    float e = expf(beta - bc[0]);
    float ws_ = e;
    for (int off = 32; off; off >>= 1) ws_ += __shfl_down(ws_, off);
    __syncthreads();
    if ((j & 63) == 0) red[j >> 6] = ws_;
    __syncthreads();
    if (j == 0) bc[1] = 1.f / (red[0] + red[1] + red[2] + red[3]);
    __syncthreads();
    alphas[i * NN + j] = e * bc[1];
}

// ---------------------------------------------------------------- K5: E_t (+EtT +ce fused)  [960 thr, j-sliced]
__global__ __launch_bounds__(960) void k_Et(const float* __restrict__ adj,
                                            const float* __restrict__ alphas,
                                            const float* __restrict__ hidden,
                                            const float* __restrict__ w_att,
                                            const float* __restrict__ b_att,
                                            float* __restrict__ Et,
                                            float* __restrict__ EtT,
                                            float* __restrict__ ce) {
    __shared__ float w_s[NN];
    __shared__ float epart[3][DD];
    __shared__ float red[16];
    int i = blockIdx.x, t = threadIdx.x, wv = t >> 6;
    if (t < NN) w_s[t] = adj[i * NN + t] * alphas[t * NN + i];
    __syncthreads();
    int d = t % 320, sl = t / 320;
    int j0 = sl * 86, j1 = (sl == 2) ? NN : (j0 + 86);
    if (d < DD) {
        float acc = 0.f;
        #pragma unroll 2
        for (int j = j0; j < j1; ++j) acc += w_s[j] * hidden[(size_t)j * DD + d];
        epart[sl][d] = acc;
    }
    __syncthreads();
    float pv = 0.f;
    if (t < DD) {
        float etv = fmaxf(epart[0][t] + epart[1][t] + epart[2][t], 0.f);
        Et[i * DD + t] = etv;
        EtT[(size_t)t * NN + i] = etv;
        pv = etv * w_att[DD + t];
    }
    for (int off = 32; off; off >>= 1) pv += __shfl_down(pv, off);
    if ((t & 63) == 0) red[wv] = pv;
    __syncthreads();
    if (t == 0) {
        float s = 0.f;
        for (int w = 0; w < 15; ++w) s += red[w];
        ce[i] = s + b_att[1];
    }
}

// ---------------------------------------------------------------- K6: S[l,n] (+cq fused) + rowmax  [768 thr, d-sliced, float4 Et rows]
__global__ __launch_bounds__(768) void k_S(const float* __restrict__ query,
                                           const float* __restrict__ Et,
                                           const float* __restrict__ w_att,
                                           const float* __restrict__ b_att,
                                           const float* __restrict__ ce,
                                           float* __restrict__ S,
                                           float* __restrict__ rowmax) {
    __shared__ alignas(16) float qw[DD];
    __shared__ float spart[3][NN];
    __shared__ float red[12];
    __shared__ float cql_s;
    int l = blockIdx.x, t = threadIdx.x, wv = t >> 6;
    float part = 0.f;
    if (t < DD) {
        float qv = query[l * DD + t];
        qw[t] = qv * w_att[2 * DD + t];
        part = qv * w_att[t];
    }
    for (int off = 32; off; off >>= 1) part += __shfl_down(part, off);
    if ((t & 63) == 0) red[wv] = part;
    __syncthreads();
    if (t == 0) {
        float s = 0.f;
        for (int w = 0; w < 12; ++w) s += red[w];
        cql_s = s + b_att[0];
    }
    __syncthreads();
    int n = t & 255, sl = t >> 8;
    {
        const float4* e4 = (const float4*)(Et + (size_t)n * DD + sl * 100);
        const float4* q4 = (const float4*)(qw + sl * 100);
        float acc = 0.f;
        #pragma unroll 5
        for (int k = 0; k < 25; ++k) {
            float4 a = e4[k], b = q4[k];
            acc += a.x * b.x; acc += a.y * b.y; acc += a.z * b.z; acc += a.w * b.w;
        }
        spart[sl][n] = acc;
    }
    __syncthreads();
    if (t < NN) {
        float val = cql_s + ce[t] + spart[0][t] + spart[1][t] + spart[2][t] + b_att[2];
        S[l * NN + t] = val;
        float wm = val;
        for (int off = 32; off; off >>= 1) wm = fmaxf(wm, __shfl_down(wm, off));
        if ((t & 63) == 0) red[t >> 6] = wm;
    }
    __syncthreads();
    if (t == 0) rowmax[l] = fmaxf(fmaxf(red[0], red[1]), fmaxf(red[2], red[3]));
}

// ---------------------------------------------------------------- K7: q2c = softmax(rowmax) @ query  (1 block)
__global__ __launch_bounds__(320) void k_q2c(const float* __restrict__ rowmax,
                                             const float* __restrict__ query,
                                             float* __restrict__ q2c) {
    __shared__ float p[LL];
    __shared__ float red[5];
    __shared__ float bc[2];
    int t = threadIdx.x;
    float v = (t < LL) ? rowmax[t] : -1e30f;
    float wm = v;
    for (int off = 32; off; off >>= 1) wm = fmaxf(wm, __shfl_down(wm, off));
    if ((t & 63) == 0) red[t >> 6] = wm;
    __syncthreads();
    if (t == 0) {
        float m = red[0];
        for (int w = 1; w < 5; ++w) m = fmaxf(m, red[w]);
        bc[0] = m;
    }
    __syncthreads();
    float e = (t < LL) ? expf(v - bc[0]) : 0.f;
    float ws_ = e;
    for (int off = 32; off; off >>= 1) ws_ += __shfl_down(ws_, off);
    __syncthreads();
    if ((t & 63) == 0) red[t >> 6] = ws_;
    __syncthreads();
    if (t == 0) {
        float s = 0.f;
        for (int w = 0; w < 5; ++w) s += red[w];
        bc[1] = 1.f / s;
    }
    __syncthreads();
    if (t < LL) p[t] = e * bc[1];
    __syncthreads();
    if (t < DD) {
        float s = 0.f;
        for (int l = 0; l < LL; ++l) s += p[l] * query[l * DD + t];
        q2c[t] = s;
    }
}

// ---------------------------------------------------------------- K8: bidaf  [960 thr: softmax -> c2q(EtT,f4) -> xs -> W_red(f4)]
__global__ __launch_bounds__(960) void k_bidaf(const float* __restrict__ S,
                                               const float* __restrict__ rowmax,
                                               const float* __restrict__ EtT,
                                               const float* __restrict__ query,
                                               const float* __restrict__ q2c,
                                               const float* __restrict__ Wred,
                                               const float* __restrict__ bred,
                                               float* __restrict__ outq) {
    __shared__ alignas(16) float p_s[NN];
    __shared__ alignas(16) float xs[D4];
    __shared__ float cpart[3][DD];
    __shared__ float rpart[3][DD];
    __shared__ float red[16];
    __shared__ float invs;
    int l = blockIdx.x, t = threadIdx.x, wv = t >> 6;
    float e = 0.f;
    if (t < NN) e = expf(S[l * NN + t] - rowmax[l]);
    float v = e;
    for (int off = 32; off; off >>= 1) v += __shfl_down(v, off);
    if ((t & 63) == 0) red[wv] = v;
    __syncthreads();
    if (t == 0) {
        float s = 0.f;
        for (int w = 0; w < 15; ++w) s += red[w];
        invs = 1.f / s;
    }
    __syncthreads();
    if (t < NN) p_s[t] = e * invs;
    __syncthreads();
    int d = t % 320, sl = t / 320;
    int j0 = sl * 88;                       // float counts 88,88,80
    int jc = (sl == 2) ? 20 : 22;           // float4 counts
    if (d < DD) {
        const float4* E4 = (const float4*)(EtT + (size_t)d * NN + j0);
        const float4* p4 = (const float4*)(p_s + j0);
        float acc = 0.f;
        #pragma unroll 4
        for (int k = 0; k < jc; ++k) {
            float4 a = E4[k], b = p4[k];
            acc += a.x * b.x; acc += a.y * b.y; acc += a.z * b.z; acc += a.w * b.w;
        }
        cpart[sl][d] = acc;
    }
    __syncthreads();
    if (t < DD) {
        float c = cpart[0][t] + cpart[1][t] + cpart[2][t];
        float qv = query[l * DD + t];
        xs[t] = qv; xs[DD + t] = c; xs[2 * DD + t] = qv * c; xs[3 * DD + t] = qv * q2c[t];
    }
    __syncthreads();
    if (d < DD) {
        const float4* w4 = (const float4*)(Wred + (size_t)d * D4 + sl * 400);
        const float4* x4 = (const float4*)(xs + sl * 400);
        float acc = 0.f;
        #pragma unroll 4
        for (int k = 0; k < 100; ++k) {
            float4 a = w4[k], b = x4[k];
            acc += a.x * b.x; acc += a.y * b.y; acc += a.z * b.z; acc += a.w * b.w;
        }
        rpart[sl][d] = acc;
    }
    __syncthreads();
    if (t < DD) outq[l * DD + t] = bred[t] + rpart[0][t] + rpart[1][t] + rpart[2][t];
}

// ---------------------------------------------------------------- K9: Xb(bf16) = [context | bin_M @ E_t | 0-pad]
__global__ __launch_bounds__(320) void k_xbuf(const float* __restrict__ ctx,
                                              const float* __restrict__ binM,
                                              const float* __restrict__ Et,
                                              ushort* __restrict__ Xb) {
    __shared__ int lst[NN];
    __shared__ int wcnt[5];
    __shared__ int total_s;
    int m = blockIdx.x, t = threadIdx.x;
    int wave = t >> 6, lane = t & 63;
    float b = (t < NN) ? binM[(size_t)m * NN + t] : 0.f;
    unsigned long long mask = __ballot(b != 0.f);
    int prefix = __popcll(mask & ((1ull << lane) - 1ull));
    if (lane == 0) wcnt[wave] = (int)__popcll(mask);
    __syncthreads();
    int wbase = 0;
    for (int w = 0; w < wave; ++w) wbase += wcnt[w];
    if (b != 0.f) lst[wbase + prefix] = t;
    if (t == 0) total_s = wcnt[0] + wcnt[1] + wcnt[2] + wcnt[3] + wcnt[4];
    __syncthreads();
    int total = total_s;
    if (t < 8) Xb[(size_t)m * KP + D2 + t] = 0;   // K padding
    if (t >= DD) return;
    Xb[(size_t)m * KP + t] = f2bf(ctx[(size_t)m * DD + t]);
    float s = 0.f;
    for (int i = 0; i < total; ++i) s += Et[(size_t)lst[i] * DD + t];
    Xb[(size_t)m * KP + DD + t] = f2bf(s);
}

// ---------------------------------------------------------------- K10: gates = Xb @ Wb^T  (bf16 MFMA, 64x64 tile)
__global__ __launch_bounds__(256) void k_gemm_gates(const ushort* __restrict__ Xb,
                                                    const ushort* __restrict__ Wb,
                                                    float* __restrict__ gates) {
    __shared__ ushort As[GM * GK];
    __shared__ ushort Bs[GN * GK];
    int m0 = blockIdx.x * GM, n0 = blockIdx.y * GN;
    int tid = threadIdx.x;
    int lane = tid & 63, w = tid >> 6;
    int wm = w >> 1, wn = w & 1;
    int l15 = lane & 15, l4 = lane >> 4;
    f32x4 acc[2][2] = {};
    int srow = tid >> 2, kslot = tid & 3;
    int sidx = srow * GK + ((kslot ^ ((srow >> 1) & 3)) << 3);
    for (int k0 = 0; k0 < KP; k0 += GK) {
        uint4 va = *(const uint4*)(Xb + (size_t)(m0 + srow) * KP + k0 + kslot * 8);
        uint4 vb = *(const uint4*)(Wb + (size_t)(n0 + srow) * KP + k0 + kslot * 8);
        *(uint4*)(As + sidx) = va;
        *(uint4*)(Bs + sidx) = vb;
        __syncthreads();
        bf16x8 af[2], bfr[2];
        #pragma unroll
        for (int mi = 0; mi < 2; ++mi) {
            int row = wm * 32 + mi * 16 + l15;
            af[mi] = *(const bf16x8*)(As + row * GK + ((l4 ^ ((row >> 1) & 3)) << 3));
        }
        #pragma unroll
        for (int ni = 0; ni < 2; ++ni) {
            int row = wn * 32 + ni * 16 + l15;
            bfr[ni] = *(const bf16x8*)(Bs + row * GK + ((l4 ^ ((row >> 1) & 3)) << 3));
        }
        #pragma unroll
        for (int mi = 0; mi < 2; ++mi)
            #pragma unroll
            for (int ni = 0; ni < 2; ++ni)
                acc[mi][ni] = __builtin_amdgcn_mfma_f32_16x16x32_bf16(af[mi], bfr[ni], acc[mi][ni], 0, 0, 0);
        __syncthreads();
    }
    #pragma unroll
    for (int mi = 0; mi < 2; ++mi) {
        #pragma unroll
        for (int ni = 0; ni < 2; ++ni) {
            int gcol = n0 + wn * 32 + ni * 16 + l15;
            int grow = m0 + wm * 32 + mi * 16 + l4 * 4;
            #pragma unroll
            for (int r = 0; r < 4; ++r)
                gates[(size_t)(grow + r) * NP + gcol] = acc[mi][ni][r];
        }
    }
}

// ---------------------------------------------------------------- K11: LSTM-cell epilogue (gates layout: i|g|o, stride NP)
__global__ __launch_bounds__(320) void k_lstm(const float* __restrict__ gates,
                                              const float* __restrict__ bih,
                                              const float* __restrict__ bhh,
                                              float* __restrict__ outc) {
    int m = blockIdx.x, d = threadIdx.x;
    if (d >= DD) return;
    const float* g = gates + (size_t)m * NP;
    float gi = g[d]          + bih[d]          + bhh[d];
    float gg = g[DD + d]     + bih[2 * DD + d] + bhh[2 * DD + d];
    float go = g[2 * DD + d] + bih[3 * DD + d] + bhh[3 * DD + d];
    float c = sigmoidf_(gi) * tanhf(gg);
    outc[m * DD + d] = sigmoidf_(go) * tanhf(c);
}

// ================================================================ launch
extern "C" void kernel_launch(void* const* d_in, const int* in_sizes, int n_in,
                              void* d_out, int out_size, void* d_ws, size_t ws_size,
                              hipStream_t stream) {
    const float* context = (const float*)d_in[0];
    const float* query   = (const float*)d_in[1];
    const float* binM    = (const float*)d_in[2];
    const float* adj     = (const float*)d_in[3];
    const float* V       = (const float*)d_in[4];
    const float* U       = (const float*)d_in[5];
    const float* bvec    = (const float*)d_in[6];
    const float* W       = (const float*)d_in[7];
    const float* w_att   = (const float*)d_in[8];
    const float* b_att   = (const float*)d_in[9];
    const float* W_red   = (const float*)d_in[10];
    const float* b_red   = (const float*)d_in[11];
    const float* W_ih    = (const float*)d_in[12];
    const float* b_ih    = (const float*)d_in[13];
    const float* b_hh    = (const float*)d_in[14];

    float* ws = (float*)d_ws;
    float* ent    = ws;                 // 153600
    float* qV     = ent    + 153600;    // 608
    float* hidden = qV     + 608;       // 76800
    float* a_i    = hidden + 76800;     // 256
    float* c_j    = a_i    + 256;       // 256
    float* alphas = c_j    + 256;       // 65536
    float* Et     = alphas + 65536;     // 76800
    float* EtT    = Et     + 76800;     // 76800
    float* ce     = EtT    + 76800;     // 256
    float* Smat   = ce     + 256;       // 32768
    float* rmax   = Smat   + 32768;     // 128
    float* q2c    = rmax   + 128;       // 304
    float* gates  = q2c    + 304;       // MM*NP = 1966080
    ushort* Xb    = (ushort*)(gates + (size_t)MM * NP);   // MM*KP ushorts
    ushort* Wb    = Xb + (size_t)MM * KP;                 // NP*KP ushorts

    float* outc = (float*)d_out;            // ctx: (M, D)
    float* outq = (float*)d_out + MM * DD;  // qry: (L, D)

    hipLaunchKernelGGL(k_convW,   dim3(NP), dim3(256), 0, stream, W_ih, Wb);
    hipLaunchKernelGGL(k_tok2ent, dim3(NN), dim3(T2E_T), 0, stream, context, binM, ent);
    hipLaunchKernelGGL(k_qprep,   dim3(1),  dim3(640), 0, stream, query, V, qV);
    hipLaunchKernelGGL(k_hidden,  dim3(NN), dim3(960), 0, stream, ent, qV, U, bvec, W, hidden, a_i, c_j);
    hipLaunchKernelGGL(k_alphas,  dim3(NN), dim3(256), 0, stream, adj, a_i, c_j, alphas);
    hipLaunchKernelGGL(k_Et,      dim3(NN), dim3(960), 0, stream, adj, alphas, hidden, w_att, b_att, Et, EtT, ce);
    hipLaunchKernelGGL(k_S,       dim3(LL), dim3(768), 0, stream, query, Et, w_att, b_att, ce, Smat, rmax);
    hipLaunchKernelGGL(k_q2c,     dim3(1),  dim3(320), 0, stream, rmax, query, q2c);
    hipLaunchKernelGGL(k_bidaf,   dim3(LL), dim3(960), 0, stream, Smat, rmax, EtT, query, q2c, W_red, b_red, outq);
    hipLaunchKernelGGL(k_xbuf,    dim3(MM), dim3(320), 0, stream, context, binM, Et, Xb);
    hipLaunchKernelGGL(k_gemm_gates, dim3(MM / GM, NP / GN), dim3(256), 0, stream, Xb, Wb, gates);
    hipLaunchKernelGGL(k_lstm,    dim3(MM), dim3(320), 0, stream, gates, b_ih, b_hh, outc);
}

// Round 6
// 156.642 us; speedup vs baseline: 1.6734x; 1.0041x over previous
//
#include <hip/hip_runtime.h>
#include <hip/hip_bf16.h>
#include <math.h>

// Problem constants
#define MM 2048   // context length
#define NN 256    // entities
#define LL 128    // query length
#define DD 300    // d2
#define D2 600    // 2*D
#define D4 1200   // 4*D
#define DROOT 17.320508075688775f

// GEMM geometry (gates = X @ Wsel^T), bf16 MFMA
#define KP 608    // K = 600 padded to 608 (19 * 32)
#define NP 960    // N = 900 (i,g,o gates) padded to 960
#define GM 64
#define GN 64
#define GK 32

typedef __attribute__((ext_vector_type(8))) short bf16x8;
typedef __attribute__((ext_vector_type(4))) float f32x4;

__device__ __forceinline__ float sigmoidf_(float x) { return 1.f / (1.f + expf(-x)); }

__device__ __forceinline__ ushort f2bf(float v) {
    union { float f; unsigned u; } x; x.f = v;
    unsigned r = x.u + 0x7fffu + ((x.u >> 16) & 1u);   // round-nearest-even
    return (ushort)(r >> 16);
}

__device__ __forceinline__ float dot4_(float4 a, float4 b) {
    return a.x * b.x + a.y * b.y + a.z * b.z + a.w * b.w;
}

__device__ __forceinline__ float wave_red_sum(float v) {
    for (int off = 32; off; off >>= 1) v += __shfl_down(v, off);
    return v;   // valid on lane 0
}

// ---------------------------------------------------------------- K0: W_ih -> bf16, rows reordered [i | g | o], K padded
__global__ __launch_bounds__(256) void k_convW(const float* __restrict__ Wih,
                                               ushort* __restrict__ Wb) {
    int r = blockIdx.x;                       // 0..959
    int src = (r < DD) ? r : r + DD;
    bool valid = (r < 3 * DD);
    for (int e = threadIdx.x; e < KP; e += 256) {
        float v = (valid && e < D2) ? Wih[(size_t)src * D2 + e] : 0.f;
        Wb[(size_t)r * KP + e] = f2bf(v);
    }
}

// ---------------------------------------------------------------- K1: tok2ent (ballot-compaction + coalesced accumulate)
#define T2E_T 512
__global__ __launch_bounds__(T2E_T) void k_tok2ent(const float* __restrict__ ctx,
                                                   const float* __restrict__ binM,
                                                   float* __restrict__ ent) {
    __shared__ int lst[MM];
    __shared__ int wcnt[T2E_T / 64];
    int n = blockIdx.x, t = threadIdx.x;
    int wave = t >> 6, lane = t & 63;
    int total = 0;
    for (int c = 0; c < MM; c += T2E_T) {
        int m = c + t;
        float b = binM[(size_t)m * NN + n];
        unsigned long long mask = __ballot(b != 0.f);
        int prefix = __popcll(mask & ((1ull << lane) - 1ull));
        if (lane == 0) wcnt[wave] = (int)__popcll(mask);
        __syncthreads();
        int wbase = total;
        for (int w = 0; w < wave; ++w) wbase += wcnt[w];
        if (b != 0.f) lst[wbase + prefix] = m;
        int chunk_total = 0;
        for (int w = 0; w < T2E_T / 64; ++w) chunk_total += wcnt[w];
        total += chunk_total;
        __syncthreads();
    }
    if (t < DD) {
        float sum = 0.f, mx = 0.f;    // max includes zeros of non-members
        int i = 0;
        for (; i + 4 <= total; i += 4) {
            float v0 = ctx[(size_t)lst[i] * DD + t];
            float v1 = ctx[(size_t)lst[i + 1] * DD + t];
            float v2 = ctx[(size_t)lst[i + 2] * DD + t];
            float v3 = ctx[(size_t)lst[i + 3] * DD + t];
            sum += v0; mx = fmaxf(mx, v0);
            sum += v1; mx = fmaxf(mx, v1);
            sum += v2; mx = fmaxf(mx, v2);
            sum += v3; mx = fmaxf(mx, v3);
        }
        for (; i < total; ++i) {
            float v = ctx[(size_t)lst[i] * DD + t];
            sum += v; mx = fmaxf(mx, v);
        }
        ent[n * D2 + t]      = sum * (1.f / MM);
        ent[n * D2 + DD + t] = mx;
    }
}

// ---------------------------------------------------------------- K2: qprep = mean-pool query then @V  (1 block)
__global__ __launch_bounds__(640) void k_qprep(const float* __restrict__ query,
                                               const float* __restrict__ V,
                                               float* __restrict__ qV) {
    __shared__ float qp[DD];
    int t = threadIdx.x;
    if (t < DD) {
        float s = 0.f;
        for (int l = 0; l < LL; ++l) s += query[l * DD + t];
        qp[t] = s * (1.f / LL);
    }
    __syncthreads();
    if (t < D2) {
        float s = 0.f;
        for (int d = 0; d < DD; ++d) s += qp[d] * V[d * D2 + t];
        qV[t] = s;
    }
}

// ---------------------------------------------------------------- K3: hidden (+gamma fused) ; a_i ; c_j
// wave-per-output dot: lanes walk U row d contiguously (coalesced), e_s in registers.
__global__ __launch_bounds__(960) void k_hidden(const float* __restrict__ ent,
                                                const float* __restrict__ qV,
                                                const float* __restrict__ U,
                                                const float* __restrict__ bvec,
                                                const float* __restrict__ W,
                                                float* __restrict__ hidden,
                                                float* __restrict__ a_i,
                                                float* __restrict__ c_j) {
    __shared__ alignas(16) float e_s[D2];
    __shared__ float h_s[DD];
    __shared__ float red[2][16];
    __shared__ float sig_s;
    int n = blockIdx.x, t = threadIdx.x, wv = t >> 6, lane = t & 63;
    float part = 0.f;
    if (t < D2) { float e = ent[n * D2 + t]; e_s[t] = e; part = e * qV[t]; }
    part = wave_red_sum(part);
    if (lane == 0) red[0][wv] = part;
    __syncthreads();
    if (t == 0) {
        float s = 0.f;
        for (int w = 0; w < 15; ++w) s += red[0][w];
        sig_s = sigmoidf_(s / DROOT);
    }
    __syncthreads();
    float sg = sig_s;
    const float4* e4 = (const float4*)e_s;          // 150 float4
    float4 eb0 = e4[lane], eb1 = e4[64 + lane];
    float4 eb2 = (lane < 22) ? e4[128 + lane] : float4{0.f, 0.f, 0.f, 0.f};
    #pragma unroll 4
    for (int i = 0; i < 20; ++i) {
        int d = wv * 20 + i;                        // 15 waves * 20 = 300
        const float4* u4 = (const float4*)(U + (size_t)d * D2);
        float4 a0 = u4[lane], a1 = u4[64 + lane];
        float p2 = dot4_(a0, eb0) + dot4_(a1, eb1);
        if (lane < 22) { float4 a2 = u4[128 + lane]; p2 += dot4_(a2, eb2); }
        p2 = wave_red_sum(p2);
        if (lane == 0) {
            float h = sg * p2 + bvec[d];
            h_s[d] = h;
            hidden[n * DD + d] = h;
        }
    }
    __syncthreads();
    float wa = 0.f, wc = 0.f;
    if (t < DD) { float h = h_s[t]; wa = h * W[t]; wc = h * W[DD + t]; }
    wa = wave_red_sum(wa); wc = wave_red_sum(wc);
    if (lane == 0) { red[0][wv] = wa; red[1][wv] = wc; }
    __syncthreads();
    if (t == 0) {
        float A = 0.f, C = 0.f;
        for (int w = 0; w < 15; ++w) { A += red[0][w]; C += red[1][w]; }
        a_i[n] = A; c_j[n] = C;
    }
}

// ---------------------------------------------------------------- K4: alphas = softmax(betas, axis=1)
__global__ __launch_bounds__(256) void k_alphas(const float* __restrict__ adj,
                                                const float* __restrict__ ai,
                                                const float* __restrict__ cj,
                                                float* __restrict__ alphas) {
    __shared__ float red[4];
    __shared__ float bc[2];
    int i = blockIdx.x, j = threadIdx.x;
    float beta = 0.f;
    if (adj[i * NN + j] > 0.f) {
        float v = ai[i] + cj[j];
        beta = (v > 0.f) ? v : 0.01f * v;
    }
    float wm = beta;
    for (int off = 32; off; off >>= 1) wm = fmaxf(wm, __shfl_down(wm, off));
    if ((j & 63) == 0) red[j >> 6] = wm;
    __syncthreads();
    if (j == 0) bc[0] = fmaxf(fmaxf(red[0], red[1]), fmaxf(red[2], red[3]));
    __syncthreads();
    float e = expf(beta - bc[0]);
    float ws_ = e;
    for (int off = 32; off; off >>= 1) ws_ += __shfl_down(ws_, off);
    __syncthreads();
    if ((j & 63) == 0) red[j >> 6] = ws_;
    __syncthreads();
    if (j == 0) bc[1] = 1.f / (red[0] + red[1] + red[2] + red[3]);
    __syncthreads();
    alphas[i * NN + j] = e * bc[1];
}

// ---------------------------------------------------------------- K5: E_t (+EtT +ce fused)  [960 thr, j-sliced, lane-coalesced]
__global__ __launch_bounds__(960) void k_Et(const float* __restrict__ adj,
                                            const float* __restrict__ alphas,
                                            const float* __restrict__ hidden,
                                            const float* __restrict__ w_att,
                                            const float* __restrict__ b_att,
                                            float* __restrict__ Et,
                                            float* __restrict__ EtT,
                                            float* __restrict__ ce) {
    __shared__ float w_s[NN];
    __shared__ float epart[3][DD];
    __shared__ float red[16];
    int i = blockIdx.x, t = threadIdx.x, wv = t >> 6;
    if (t < NN) w_s[t] = adj[i * NN + t] * alphas[t * NN + i];
    __syncthreads();
    int d = t % 320, sl = t / 320;
    int j0 = sl * 86, j1 = (sl == 2) ? NN : (j0 + 86);
    if (d < DD) {
        float acc = 0.f;
        #pragma unroll 2
        for (int j = j0; j < j1; ++j) acc += w_s[j] * hidden[(size_t)j * DD + d];
        epart[sl][d] = acc;
    }
    __syncthreads();
    float pv = 0.f;
    if (t < DD) {
        float etv = fmaxf(epart[0][t] + epart[1][t] + epart[2][t], 0.f);
        Et[i * DD + t] = etv;
        EtT[(size_t)t * NN + i] = etv;
        pv = etv * w_att[DD + t];
    }
    pv = wave_red_sum(pv);
    if ((t & 63) == 0) red[wv] = pv;
    __syncthreads();
    if (t == 0) {
        float s = 0.f;
        for (int w = 0; w < 15; ++w) s += red[w];
        ce[i] = s + b_att[1];
    }
}

// ---------------------------------------------------------------- K6: S[l,n] (+cq fused) + rowmax  [1024 thr, wave-per-n dot]
__global__ __launch_bounds__(1024) void k_S(const float* __restrict__ query,
                                            const float* __restrict__ Et,
                                            const float* __restrict__ w_att,
                                            const float* __restrict__ b_att,
                                            const float* __restrict__ ce,
                                            float* __restrict__ S,
                                            float* __restrict__ rowmax) {
    __shared__ alignas(16) float qw[DD];
    __shared__ float red[16];
    __shared__ float cql_s;
    int l = blockIdx.x, t = threadIdx.x, wv = t >> 6, lane = t & 63;
    float part = 0.f;
    if (t < DD) {
        float qv = query[l * DD + t];
        qw[t] = qv * w_att[2 * DD + t];
        part = qv * w_att[t];
    }
    part = wave_red_sum(part);
    if (lane == 0) red[wv] = part;
    __syncthreads();
    if (t == 0) {
        float s = 0.f;
        for (int w = 0; w < 16; ++w) s += red[w];
        cql_s = s + b_att[0];
    }
    __syncthreads();
    const float4* q4 = (const float4*)qw;           // 75 float4
    float4 qb0 = q4[lane];
    float4 qb1 = (lane < 11) ? q4[64 + lane] : float4{0.f, 0.f, 0.f, 0.f};
    float wmax = -1e30f;
    #pragma unroll 4
    for (int i = 0; i < 16; ++i) {
        int n = wv * 16 + i;                        // 16 waves * 16 = 256
        const float4* e4 = (const float4*)(Et + (size_t)n * DD);
        float4 a0 = e4[lane];
        float p2 = dot4_(a0, qb0);
        if (lane < 11) { float4 a1 = e4[64 + lane]; p2 += dot4_(a1, qb1); }
        p2 = wave_red_sum(p2);
        if (lane == 0) {
            float val = cql_s + ce[n] + p2 + b_att[2];
            S[l * NN + n] = val;
            wmax = fmaxf(wmax, val);
        }
    }
    if (lane == 0) red[wv] = wmax;
    __syncthreads();
    if (t == 0) {
        float m = red[0];
        for (int w = 1; w < 16; ++w) m = fmaxf(m, red[w]);
        rowmax[l] = m;
    }
}

// ---------------------------------------------------------------- K7: q2c = softmax(rowmax) @ query  (1 block)
__global__ __launch_bounds__(320) void k_q2c(const float* __restrict__ rowmax,
                                             const float* __restrict__ query,
                                             float* __restrict__ q2c) {
    __shared__ float p[LL];
    __shared__ float red[5];
    __shared__ float bc[2];
    int t = threadIdx.x;
    float v = (t < LL) ? rowmax[t] : -1e30f;
    float wm = v;
    for (int off = 32; off; off >>= 1) wm = fmaxf(wm, __shfl_down(wm, off));
    if ((t & 63) == 0) red[t >> 6] = wm;
    __syncthreads();
    if (t == 0) {
        float m = red[0];
        for (int w = 1; w < 5; ++w) m = fmaxf(m, red[w]);
        bc[0] = m;
    }
    __syncthreads();
    float e = (t < LL) ? expf(v - bc[0]) : 0.f;
    float ws_ = e;
    for (int off = 32; off; off >>= 1) ws_ += __shfl_down(ws_, off);
    __syncthreads();
    if ((t & 63) == 0) red[t >> 6] = ws_;
    __syncthreads();
    if (t == 0) {
        float s = 0.f;
        for (int w = 0; w < 5; ++w) s += red[w];
        bc[1] = 1.f / s;
    }
    __syncthreads();
    if (t < LL) p[t] = e * bc[1];
    __syncthreads();
    if (t < DD) {
        float s = 0.f;
        for (int l = 0; l < LL; ++l) s += p[l] * query[l * DD + t];
        q2c[t] = s;
    }
}

// ---------------------------------------------------------------- K8: bidaf  [960 thr, wave-per-output coalesced dots]
__global__ __launch_bounds__(960) void k_bidaf(const float* __restrict__ S,
                                               const float* __restrict__ rowmax,
                                               const float* __restrict__ EtT,
                                               const float* __restrict__ query,
                                               const float* __restrict__ q2c,
                                               const float* __restrict__ Wred,
                                               const float* __restrict__ bred,
                                               float* __restrict__ outq) {
    __shared__ alignas(16) float p_s[NN];
    __shared__ alignas(16) float xs[D4];
    __shared__ float cq_s[DD];
    __shared__ float red[16];
    __shared__ float invs;
    int l = blockIdx.x, t = threadIdx.x, wv = t >> 6, lane = t & 63;
    float e = 0.f;
    if (t < NN) e = expf(S[l * NN + t] - rowmax[l]);
    float v = wave_red_sum(e);
    if (lane == 0) red[wv] = v;
    __syncthreads();
    if (t == 0) {
        float s = 0.f;
        for (int w = 0; w < 15; ++w) s += red[w];
        invs = 1.f / s;
    }
    __syncthreads();
    if (t < NN) p_s[t] = e * invs;
    __syncthreads();
    // c2q: wave-per-d over EtT rows (256 floats = 64 float4, one per lane)
    const float4* p4 = (const float4*)p_s;
    float4 pb = p4[lane];
    #pragma unroll 4
    for (int i = 0; i < 20; ++i) {
        int d = wv * 20 + i;                        // 15 * 20 = 300
        float4 a = ((const float4*)(EtT + (size_t)d * NN))[lane];
        float p2 = wave_red_sum(dot4_(a, pb));
        if (lane == 0) cq_s[d] = p2;
    }
    __syncthreads();
    if (t < DD) {
        float c = cq_s[t];
        float qv = query[l * DD + t];
        xs[t] = qv; xs[DD + t] = c; xs[2 * DD + t] = qv * c; xs[3 * DD + t] = qv * q2c[t];
    }
    __syncthreads();
    // W_red: wave-per-d over Wred rows (1200 floats = 300 float4 = 64*4 + 44)
    const float4* x4 = (const float4*)xs;
    float4 xb0 = x4[lane], xb1 = x4[64 + lane], xb2 = x4[128 + lane], xb3 = x4[192 + lane];
    float4 xb4 = (lane < 44) ? x4[256 + lane] : float4{0.f, 0.f, 0.f, 0.f};
    #pragma unroll 2
    for (int i = 0; i < 20; ++i) {
        int d = wv * 20 + i;
        const float4* w4 = (const float4*)(Wred + (size_t)d * D4);
        float4 a0 = w4[lane], a1 = w4[64 + lane], a2 = w4[128 + lane], a3 = w4[192 + lane];
        float p2 = dot4_(a0, xb0) + dot4_(a1, xb1) + dot4_(a2, xb2) + dot4_(a3, xb3);
        if (lane < 44) { float4 a4 = w4[256 + lane]; p2 += dot4_(a4, xb4); }
        p2 = wave_red_sum(p2);
        if (lane == 0) outq[l * DD + d] = bred[d] + p2;
    }
}

// ---------------------------------------------------------------- K9: Xb(bf16) = [context | bin_M @ E_t | 0-pad]
__global__ __launch_bounds__(320) void k_xbuf(const float* __restrict__ ctx,
                                              const float* __restrict__ binM,
                                              const float* __restrict__ Et,
                                              ushort* __restrict__ Xb) {
    __shared__ int lst[NN];
    __shared__ int wcnt[5];
    __shared__ int total_s;
    int m = blockIdx.x, t = threadIdx.x;
    int wave = t >> 6, lane = t & 63;
    float b = (t < NN) ? binM[(size_t)m * NN + t] : 0.f;
    unsigned long long mask = __ballot(b != 0.f);
    int prefix = __popcll(mask & ((1ull << lane) - 1ull));
    if (lane == 0) wcnt[wave] = (int)__popcll(mask);
    __syncthreads();
    int wbase = 0;
    for (int w = 0; w < wave; ++w) wbase += wcnt[w];
    if (b != 0.f) lst[wbase + prefix] = t;
    if (t == 0) total_s = wcnt[0] + wcnt[1] + wcnt[2] + wcnt[3] + wcnt[4];
    __syncthreads();
    int total = total_s;
    if (t < 8) Xb[(size_t)m * KP + D2 + t] = 0;   // K padding
    if (t >= DD) return;
    Xb[(size_t)m * KP + t] = f2bf(ctx[(size_t)m * DD + t]);
    float s = 0.f;
    for (int i = 0; i < total; ++i) s += Et[(size_t)lst[i] * DD + t];
    Xb[(size_t)m * KP + DD + t] = f2bf(s);
}

// ---------------------------------------------------------------- K10: gates = Xb @ Wb^T  (bf16 MFMA, 64x64 tile)
__global__ __launch_bounds__(256) void k_gemm_gates(const ushort* __restrict__ Xb,
                                                    const ushort* __restrict__ Wb,
                                                    float* __restrict__ gates) {
    __shared__ ushort As[GM * GK];
    __shared__ ushort Bs[GN * GK];
    int m0 = blockIdx.x * GM, n0 = blockIdx.y * GN;
    int tid = threadIdx.x;
    int lane = tid & 63, w = tid >> 6;
    int wm = w >> 1, wn = w & 1;
    int l15 = lane & 15, l4 = lane >> 4;
    f32x4 acc[2][2] = {};
    int srow = tid >> 2, kslot = tid & 3;
    int sidx = srow * GK + ((kslot ^ ((srow >> 1) & 3)) << 3);
    for (int k0 = 0; k0 < KP; k0 += GK) {
        uint4 va = *(const uint4*)(Xb + (size_t)(m0 + srow) * KP + k0 + kslot * 8);
        uint4 vb = *(const uint4*)(Wb + (size_t)(n0 + srow) * KP + k0 + kslot * 8);
        *(uint4*)(As + sidx) = va;
        *(uint4*)(Bs + sidx) = vb;
        __syncthreads();
        bf16x8 af[2], bfr[2];
        #pragma unroll
        for (int mi = 0; mi < 2; ++mi) {
            int row = wm * 32 + mi * 16 + l15;
            af[mi] = *(const bf16x8*)(As + row * GK + ((l4 ^ ((row >> 1) & 3)) << 3));
        }
        #pragma unroll
        for (int ni = 0; ni < 2; ++ni) {
            int row = wn * 32 + ni * 16 + l15;
            bfr[ni] = *(const bf16x8*)(Bs + row * GK + ((l4 ^ ((row >> 1) & 3)) << 3));
        }
        #pragma unroll
        for (int mi = 0; mi < 2; ++mi)
            #pragma unroll
            for (int ni = 0; ni < 2; ++ni)
                acc[mi][ni] = __builtin_amdgcn_mfma_f32_16x16x32_bf16(af[mi], bfr[ni], acc[mi][ni], 0, 0, 0);
        __syncthreads();
    }
    #pragma unroll
    for (int mi = 0; mi < 2; ++mi) {
        #pragma unroll
        for (int ni = 0; ni < 2; ++ni) {
            int gcol = n0 + wn * 32 + ni * 16 + l15;
            int grow = m0 + wm * 32 + mi * 16 + l4 * 4;
            #pragma unroll
            for (int r = 0; r < 4; ++r)
                gates[(size_t)(grow + r) * NP + gcol] = acc[mi][ni][r];
        }
    }
}

// ---------------------------------------------------------------- K11: LSTM-cell epilogue (gates layout: i|g|o, stride NP)
__global__ __launch_bounds__(320) void k_lstm(const float* __restrict__ gates,
                                              const float* __restrict__ bih,
                                              const float* __restrict__ bhh,
                                              float* __restrict__ outc) {
    int m = blockIdx.x, d = threadIdx.x;
    if (d >= DD) return;
    const float* g = gates + (size_t)m * NP;
    float gi = g[d]          + bih[d]          + bhh[d];
    float gg = g[DD + d]     + bih[2 * DD + d] + bhh[2 * DD + d];
    float go = g[2 * DD + d] + bih[3 * DD + d] + bhh[3 * DD + d];
    float c = sigmoidf_(gi) * tanhf(gg);
    outc[m * DD + d] = sigmoidf_(go) * tanhf(c);
}

// ================================================================ launch
extern "C" void kernel_launch(void* const* d_in, const int* in_sizes, int n_in,
                              void* d_out, int out_size, void* d_ws, size_t ws_size,
                              hipStream_t stream) {
    const float* context = (const float*)d_in[0];
    const float* query   = (const float*)d_in[1];
    const float* binM    = (const float*)d_in[2];
    const float* adj     = (const float*)d_in[3];
    const float* V       = (const float*)d_in[4];
    const float* U       = (const float*)d_in[5];
    const float* bvec    = (const float*)d_in[6];
    const float* W       = (const float*)d_in[7];
    const float* w_att   = (const float*)d_in[8];
    const float* b_att   = (const float*)d_in[9];
    const float* W_red   = (const float*)d_in[10];
    const float* b_red   = (const float*)d_in[11];
    const float* W_ih    = (const float*)d_in[12];
    const float* b_ih    = (const float*)d_in[13];
    const float* b_hh    = (const float*)d_in[14];

    float* ws = (float*)d_ws;
    float* ent    = ws;                 // 153600
    float* qV     = ent    + 153600;    // 608
    float* hidden = qV     + 608;       // 76800
    float* a_i    = hidden + 76800;     // 256
    float* c_j    = a_i    + 256;       // 256
    float* alphas = c_j    + 256;       // 65536
    float* Et     = alphas + 65536;     // 76800
    float* EtT    = Et     + 76800;     // 76800
    float* ce     = EtT    + 76800;     // 256
    float* Smat   = ce     + 256;       // 32768
    float* rmax   = Smat   + 32768;     // 128
    float* q2c    = rmax   + 128;       // 304
    float* gates  = q2c    + 304;       // MM*NP = 1966080
    ushort* Xb    = (ushort*)(gates + (size_t)MM * NP);   // MM*KP ushorts
    ushort* Wb    = Xb + (size_t)MM * KP;                 // NP*KP ushorts

    float* outc = (float*)d_out;            // ctx: (M, D)
    float* outq = (float*)d_out + MM * DD;  // qry: (L, D)

    hipLaunchKernelGGL(k_convW,   dim3(NP), dim3(256), 0, stream, W_ih, Wb);
    hipLaunchKernelGGL(k_tok2ent, dim3(NN), dim3(T2E_T), 0, stream, context, binM, ent);
    hipLaunchKernelGGL(k_qprep,   dim3(1),  dim3(640), 0, stream, query, V, qV);
    hipLaunchKernelGGL(k_hidden,  dim3(NN), dim3(960), 0, stream, ent, qV, U, bvec, W, hidden, a_i, c_j);
    hipLaunchKernelGGL(k_alphas,  dim3(NN), dim3(256), 0, stream, adj, a_i, c_j, alphas);
    hipLaunchKernelGGL(k_Et,      dim3(NN), dim3(960), 0, stream, adj, alphas, hidden, w_att, b_att, Et, EtT, ce);
    hipLaunchKernelGGL(k_S,       dim3(LL), dim3(1024), 0, stream, query, Et, w_att, b_att, ce, Smat, rmax);
    hipLaunchKernelGGL(k_q2c,     dim3(1),  dim3(320), 0, stream, rmax, query, q2c);
    hipLaunchKernelGGL(k_bidaf,   dim3(LL), dim3(960), 0, stream, Smat, rmax, EtT, query, q2c, W_red, b_red, outq);
    hipLaunchKernelGGL(k_xbuf,    dim3(MM), dim3(320), 0, stream, context, binM, Et, Xb);
    hipLaunchKernelGGL(k_gemm_gates, dim3(MM / GM, NP / GN), dim3(256), 0, stream, Xb, Wb, gates);
    hipLaunchKernelGGL(k_lstm,    dim3(MM), dim3(320), 0, stream, gates, b_ih, b_hh, outc);
}